// Round 1
// baseline (1577.725 us; speedup 1.0000x reference)
//
#include <hip/hip_runtime.h>
#include <stdint.h>

#define M_TOK   8192
#define DMODEL  1024
#define DDICT   16384
#define TOPK    32
#define WANT    48      // candidate superset size target
#define MAXC    256     // candidate capacity

typedef __attribute__((ext_vector_type(8))) short bf16x8;
typedef __attribute__((ext_vector_type(4))) float f32x4;

// ---------------------------------------------------------------- helpers
__device__ __forceinline__ unsigned short f32_to_bf16(float f) {
  unsigned u = __float_as_uint(f);
  unsigned r = 0x7FFFu + ((u >> 16) & 1u);   // round-to-nearest-even
  return (unsigned short)((u + r) >> 16);
}

#define GLD16(g, l)                                                        \
  __builtin_amdgcn_global_load_lds(                                        \
      (const __attribute__((address_space(1))) void*)(g),                  \
      (__attribute__((address_space(3))) void*)(l), 16, 0, 0)

// ---------------------------------------------------------------- casts
__global__ __launch_bounds__(256) void cast_bf16_kernel(
    const float* __restrict__ in, unsigned short* __restrict__ out, int n4) {
  int i = blockIdx.x * 256 + threadIdx.x;
  if (i >= n4) return;
  float4 v = ((const float4*)in)[i];
  ushort4 o;
  o.x = f32_to_bf16(v.x); o.y = f32_to_bf16(v.y);
  o.z = f32_to_bf16(v.z); o.w = f32_to_bf16(v.w);
  ((ushort4*)out)[i] = o;
}

// W_dec [DMODEL, DDICT] -> W_decT [DDICT, DMODEL]
__global__ __launch_bounds__(256) void transpose_kernel(
    const float* __restrict__ in, float* __restrict__ out) {
  __shared__ float tile[32][33];
  int tx = threadIdx.x & 31;
  int ty = threadIdx.x >> 5;            // 0..7
  int c0 = blockIdx.x * 32;             // col base in 'in'
  int r0 = blockIdx.y * 32;             // row base in 'in'
#pragma unroll
  for (int i = 0; i < 32; i += 8)
    tile[ty + i][tx] = in[(size_t)(r0 + ty + i) * DDICT + c0 + tx];
  __syncthreads();
#pragma unroll
  for (int i = 0; i < 32; i += 8)
    out[(size_t)(c0 + ty + i) * DMODEL + r0 + tx] = tile[tx][ty + i];
}

// ---------------------------------------------------------------- encoder GEMM
// C[M, DDICT] = A[M, K] * B[DDICT, K]^T + bias   (A,B bf16; C fp32)
// 128x128 tile, BK=32, 256 thr = 4 waves (2x2), wave = 64x64 = 4x4 MFMA 16x16x32
__global__ __launch_bounds__(256) void gemm_enc_kernel(
    const unsigned short* __restrict__ A,
    const unsigned short* __restrict__ B,
    const float* __restrict__ bias,
    float* __restrict__ C) {
  __shared__ __align__(16) unsigned short As[128 * 32];  // 8 KB
  __shared__ __align__(16) unsigned short Bs[128 * 32];  // 8 KB

  const int tid  = threadIdx.x;
  const int lane = tid & 63;
  const int wave = tid >> 6;
  const int l16  = lane & 15;
  const int quad = lane >> 4;

  const int bm = blockIdx.y * 128;
  const int bn = blockIdx.x * 128;
  const int wm = (wave >> 1) * 64;
  const int wn = (wave & 1) * 64;

  // staging: 512 chunks of 16B per tile, 2 per thread. chunk c -> row c>>2, kbyte (c&3)*16
  const int c0 = tid, c1 = tid + 256;
  const int row0 = c0 >> 2, ke0 = (c0 & 3) * 8;  // k offset in elements
  const int row1 = c1 >> 2, ke1 = (c1 & 3) * 8;

  const unsigned short* Ab = A + (size_t)bm * DMODEL;
  const unsigned short* Bb = B + (size_t)bn * DMODEL;

  f32x4 acc[4][4];
#pragma unroll
  for (int i = 0; i < 4; ++i)
#pragma unroll
    for (int j = 0; j < 4; ++j) acc[i][j] = f32x4{0.f, 0.f, 0.f, 0.f};

  for (int k0 = 0; k0 < DMODEL; k0 += 32) {
    GLD16(Ab + (size_t)row0 * DMODEL + k0 + ke0, As + c0 * 8);
    GLD16(Ab + (size_t)row1 * DMODEL + k0 + ke1, As + c1 * 8);
    GLD16(Bb + (size_t)row0 * DMODEL + k0 + ke0, Bs + c0 * 8);
    GLD16(Bb + (size_t)row1 * DMODEL + k0 + ke1, Bs + c1 * 8);
    __syncthreads();  // drains vmcnt (global_load_lds) then barrier

    bf16x8 a[4], b[4];
#pragma unroll
    for (int i = 0; i < 4; ++i) {
      a[i] = *(const bf16x8*)(As + (wm + i * 16 + l16) * 32 + quad * 8);
      b[i] = *(const bf16x8*)(Bs + (wn + i * 16 + l16) * 32 + quad * 8);
    }
#pragma unroll
    for (int i = 0; i < 4; ++i)
#pragma unroll
      for (int j = 0; j < 4; ++j)
        acc[i][j] = __builtin_amdgcn_mfma_f32_16x16x32_bf16(a[i], b[j], acc[i][j], 0, 0, 0);
    __syncthreads();
  }

  // epilogue: C[m][n], m = wm+i*16+quad*4+r, n = wn+j*16+l16
  float* Cb = C + (size_t)bm * DDICT + bn;
#pragma unroll
  for (int j = 0; j < 4; ++j) {
    int col = wn + j * 16 + l16;
    float bv = bias[bn + col];
#pragma unroll
    for (int i = 0; i < 4; ++i)
#pragma unroll
      for (int r = 0; r < 4; ++r) {
        int rowi = wm + i * 16 + quad * 4 + r;
        Cb[(size_t)rowi * DDICT + col] = acc[i][j][r] + bv;
      }
  }
}

// ---------------------------------------------------------------- select + refine + decode
// One block per token row. Reads approx z (out_z), zeros the row, finds >=WANT
// candidates by |z| bits, recomputes exact fp64 dots, picks exact top-32
// (tie: lower index), scatters fp32 values, computes recon.
__global__ __launch_bounds__(256) void select_kernel(
    const float* __restrict__ x,
    const float* __restrict__ Wenc,
    const float* __restrict__ benc,
    const float* __restrict__ WdT,
    const float* __restrict__ bdec,
    float* __restrict__ out_recon,
    float* __restrict__ out_z) {
  const int row  = blockIdx.x;
  const int tid  = threadIdx.x;
  const int lane = tid & 63;
  const int wave = tid >> 6;

  __shared__ float    xs[DMODEL];      // 4 KB
  __shared__ int      s_cidx[MAXC];
  __shared__ double   s_cval[MAXC];
  __shared__ int      s_selc[TOPK];
  __shared__ unsigned s_red[4];
  __shared__ unsigned s_cnt;

  float* zrow = out_z + (size_t)row * DDICT;

  // phase 1: load |z| bit-keys into registers (64/thread), zero the row
  uint4 keys[16];
  {
    const float4* zp = (const float4*)zrow;
    float4* zw = (float4*)zrow;
    float4 z4 = make_float4(0.f, 0.f, 0.f, 0.f);
#pragma unroll
    for (int i = 0; i < 16; ++i) {
      float4 v = zp[tid + i * 256];
      uint4 k;
      k.x = __float_as_uint(v.x) & 0x7FFFFFFFu;
      k.y = __float_as_uint(v.y) & 0x7FFFFFFFu;
      k.z = __float_as_uint(v.z) & 0x7FFFFFFFu;
      k.w = __float_as_uint(v.w) & 0x7FFFFFFFu;
      keys[i] = k;
      zw[tid + i * 256] = z4;
    }
  }
  ((float4*)xs)[tid] = ((const float4*)(x + (size_t)row * DMODEL))[tid];
  if (tid == 0) s_cnt = 0;
  __syncthreads();

  // phase 2: binary search threshold T so count(key >= T) >= WANT (tight)
  unsigned lo = 0u, hi = 0x7F800000u;  // invariant: cnt(lo) >= WANT > cnt(hi)
  for (int it = 0; it < 26; ++it) {
    unsigned mid = (lo + hi) >> 1;
    int c = 0;
#pragma unroll
    for (int i = 0; i < 16; ++i)
      c += (keys[i].x >= mid) + (keys[i].y >= mid) +
           (keys[i].z >= mid) + (keys[i].w >= mid);
#pragma unroll
    for (int off = 32; off; off >>= 1) c += __shfl_down(c, off);
    if (lane == 0) s_red[wave] = (unsigned)c;
    __syncthreads();
    unsigned tot = s_red[0] + s_red[1] + s_red[2] + s_red[3];
    __syncthreads();
    if (tot >= WANT) lo = mid; else hi = mid;
  }
  const unsigned T = lo;

  // phase 3: collect candidate indices
#pragma unroll
  for (int i = 0; i < 16; ++i) {
    int base = i * 1024 + tid * 4;
    if (keys[i].x >= T) { unsigned p = atomicAdd(&s_cnt, 1u); if (p < MAXC) s_cidx[p] = base + 0; }
    if (keys[i].y >= T) { unsigned p = atomicAdd(&s_cnt, 1u); if (p < MAXC) s_cidx[p] = base + 1; }
    if (keys[i].z >= T) { unsigned p = atomicAdd(&s_cnt, 1u); if (p < MAXC) s_cidx[p] = base + 2; }
    if (keys[i].w >= T) { unsigned p = atomicAdd(&s_cnt, 1u); if (p < MAXC) s_cidx[p] = base + 3; }
  }
  __syncthreads();
  const int ncand = (int)(s_cnt < (unsigned)MAXC ? s_cnt : (unsigned)MAXC);

  // phase 4: exact fp64 dot per candidate (one wave per candidate)
  for (int c = wave; c < ncand; c += 4) {
    const int j = s_cidx[c];
    const float* wr = Wenc + (size_t)j * DMODEL;
    double s = 0.0;
#pragma unroll
    for (int t = 0; t < 16; ++t)
      s += (double)xs[lane + t * 64] * (double)wr[lane + t * 64];
#pragma unroll
    for (int off = 32; off; off >>= 1) s += __shfl_down(s, off);
    if (lane == 0) s_cval[c] = s + (double)benc[j];
  }
  __syncthreads();

  // phase 5: exact top-32 by |val| (tie: lower dict index), wave 0 only
  if (wave == 0) {
    double va[4]; int jj[4], cp[4]; bool alive[4];
#pragma unroll
    for (int s = 0; s < 4; ++s) {
      int c = lane + s * 64;
      bool ok = c < ncand;
      alive[s] = ok;
      va[s] = ok ? fabs(s_cval[c]) : -1.0;
      jj[s] = ok ? s_cidx[c] : 0x7FFFFFFF;
      cp[s] = c;
    }
    for (int pick = 0; pick < TOPK; ++pick) {
      double ba = -1.0; int bj = 0x7FFFFFFF, bc = -1, bslot = -1;
#pragma unroll
      for (int s = 0; s < 4; ++s)
        if (alive[s] && (va[s] > ba || (va[s] == ba && jj[s] < bj))) {
          ba = va[s]; bj = jj[s]; bc = cp[s]; bslot = s;
        }
      int myc = bc, myslot = bslot;
#pragma unroll
      for (int off = 32; off; off >>= 1) {
        double oa = __shfl_down(ba, off);
        int    oj = __shfl_down(bj, off);
        int    oc = __shfl_down(bc, off);
        if (oa > ba || (oa == ba && oj < bj)) { ba = oa; bj = oj; bc = oc; }
      }
      bc = __shfl(bc, 0);
      if (myc == bc && myslot >= 0) alive[myslot] = false;
      if (lane == 0) s_selc[pick] = bc;
    }
  }
  __syncthreads();

  // phase 6: scatter refined z values (zero-stores already drained by barriers)
  if (tid < TOPK) {
    int c = s_selc[tid];
    zrow[s_cidx[c]] = (float)s_cval[c];
  }

  // phase 7: fused sparse decode. thread owns dims [4*tid, 4*tid+3]
  float a0, a1, a2, a3;
  {
    float4 b4 = ((const float4*)bdec)[tid];
    a0 = b4.x; a1 = b4.y; a2 = b4.z; a3 = b4.w;
  }
#pragma unroll 4
  for (int p = 0; p < TOPK; ++p) {
    int c = s_selc[p];
    int j = s_cidx[c];
    float zv = (float)s_cval[c];
    float4 wv = ((const float4*)(WdT + (size_t)j * DMODEL))[tid];
    a0 = fmaf(zv, wv.x, a0); a1 = fmaf(zv, wv.y, a1);
    a2 = fmaf(zv, wv.z, a2); a3 = fmaf(zv, wv.w, a3);
  }
  ((float4*)(out_recon + (size_t)row * DMODEL))[tid] = make_float4(a0, a1, a2, a3);
}

// ---------------------------------------------------------------- launch
extern "C" void kernel_launch(void* const* d_in, const int* in_sizes, int n_in,
                              void* d_out, int out_size, void* d_ws, size_t ws_size,
                              hipStream_t stream) {
  const float* x    = (const float*)d_in[0];
  const float* Wenc = (const float*)d_in[1];
  const float* benc = (const float*)d_in[2];
  const float* Wdec = (const float*)d_in[3];
  const float* bdec = (const float*)d_in[4];

  float* out_recon = (float*)d_out;
  float* out_z     = (float*)d_out + (size_t)M_TOK * DMODEL;

  // workspace carve: x_bf16 (16 MB) | Wenc_bf16 (33.5 MB) | W_decT (67 MB)
  char* w = (char*)d_ws;
  unsigned short* xbf = (unsigned short*)w;
  unsigned short* wbf = (unsigned short*)(w + (size_t)M_TOK * DMODEL * 2);
  float* wdT = (float*)(w + (size_t)M_TOK * DMODEL * 2 + (size_t)DDICT * DMODEL * 2);

  {
    int n4 = M_TOK * DMODEL / 4;
    cast_bf16_kernel<<<(n4 + 255) / 256, 256, 0, stream>>>(x, xbf, n4);
  }
  {
    int n4 = DDICT * DMODEL / 4;
    cast_bf16_kernel<<<(n4 + 255) / 256, 256, 0, stream>>>(Wenc, wbf, n4);
  }
  {
    dim3 g(DDICT / 32, DMODEL / 32);
    transpose_kernel<<<g, 256, 0, stream>>>(Wdec, wdT);
  }
  {
    dim3 g(DDICT / 128, M_TOK / 128);
    gemm_enc_kernel<<<g, 256, 0, stream>>>(xbf, wbf, benc, out_z);
  }
  select_kernel<<<M_TOK, 256, 0, stream>>>(x, Wenc, benc, wdT, bdec, out_recon, out_z);
}